// Round 8
// baseline (262.675 us; speedup 1.0000x reference)
//
#include <hip/hip_runtime.h>
#include <math.h>

#define Kk 8
#define Bb 32
#define Cc 3
#define HW 36864          // 192*192
#define HW2 18432         // HW/2 (float2s per plane)
#define CHW 110592        // 3*HW
#define CHW4 27648        // CHW/4
#define BCHW 3538944      // B*C*HW
#define OUTMAIN 31850496  // 9*BCHW : index tail start in d_out (elements)
#define NCH 72            // chunks per batch in k_red (512 px each)
#define PARTN 1728        // 24*NCH per batch
#define INVVAR 11.11111111111111f
#define EPSf 1e-5f

__device__ __forceinline__ int clampK(int v) { return v < 0 ? 0 : (v > Kk - 1 ? Kk - 1 : v); }
__device__ __forceinline__ float2 ld2(const float* p) { return *reinterpret_cast<const float2*>(p); }
__device__ __forceinline__ void st2(float* p, float2 v) { *reinterpret_cast<float2*>(p) = v; }
__device__ __forceinline__ float4 ld4(const float* p) { return *reinterpret_cast<const float4*>(p); }

// ---------------------------------------------------------------------------
// Kernel 1: recon -> out[0]  AND  sd = shp * sum_c (apc-img)^2.
// float2/thread -> 2304 blocks (9 waves/SIMD supply for latency hiding).
// ---------------------------------------------------------------------------
__global__ __launch_bounds__(256) void k_pre_fused(
    const float* __restrict__ images, const float* __restrict__ apc,
    const float* __restrict__ shp, const float* __restrict__ zeta,
    const float* __restrict__ back, float* __restrict__ out,
    float* __restrict__ sd)
{
    int gid = blockIdx.x * 256 + threadIdx.x;     // float2 id over B*HW2
    int b = gid / HW2;
    int pix = (gid - b * HW2) * 2;

    float2 img[Cc], bk[Cc], rec[Cc];
#pragma unroll
    for (int c = 0; c < Cc; ++c) {
        img[c] = ld2(images + (size_t)(b * Cc + c) * HW + pix);
        bk[c]  = ld2(back   + (size_t)(b * Cc + c) * HW + pix);
        rec[c] = make_float2(0.f, 0.f);
    }
    float cum0 = 1.f, cum1 = 1.f;

#pragma unroll
    for (int k = 0; k < Kk; ++k) {
        float2 s = ld2(shp + (size_t)(k * Bb + b) * HW + pix);
        float z = zeta[k * Bb + b];
        float x0 = s.x * z, x1 = s.y * z;
        float g0 = x0 * cum0, g1 = x1 * cum1;
        float df0 = 0.f, df1 = 0.f;
#pragma unroll
        for (int c = 0; c < Cc; ++c) {
            float2 a = ld2(apc + ((size_t)(k * Bb + b) * Cc + c) * HW + pix);
            float d0 = a.x - img[c].x, d1 = a.y - img[c].y;
            df0 += d0 * d0; df1 += d1 * d1;
            rec[c].x += g0 * a.x; rec[c].y += g1 * a.y;
        }
        st2(sd + (size_t)(k * Bb + b) * HW + pix, make_float2(s.x * df0, s.y * df1));
        cum0 *= (1.f - x0); cum1 *= (1.f - x1);
    }
#pragma unroll
    for (int c = 0; c < Cc; ++c) {
        st2(out + (size_t)(b * Cc + c) * HW + pix,
            make_float2(rec[c].x + cum0 * bk[c].x, rec[c].y + cum1 * bk[c].y));
    }
}

// ---------------------------------------------------------------------------
// Kernel 2 (step t): [t>0: inline score of step t-1 from partials_prev ->
// sel, write idxf[t-1] from (ch==0) block], update persistent P, reduce
// {sum sd*P, sum shp*P, max shp*P}. float2/thread, 2304 blocks, LDS tree
// (no shuffles). partials layout: [b][24][NCH].
// ---------------------------------------------------------------------------
__global__ __launch_bounds__(256) void k_red_fast(
    const float* __restrict__ shp, const float* __restrict__ sd,
    float* __restrict__ Pbuf, float* idxf, const float* __restrict__ zeta,
    const float* __restrict__ partials_prev, float* __restrict__ partials_cur,
    int t)
{
    int b = blockIdx.x / NCH, ch = blockIdx.x % NCH;
    int tid = threadIdx.x;

    __shared__ float svals[24];
    __shared__ int s_sel;
    int sel = 0;
    if (t > 0) {
        if (tid < 24) {
            int comp = tid % 3;
            float v = (comp == 2) ? -1e30f : 0.f;
            for (int j = 0; j < NCH; ++j) {
                float x = partials_prev[(size_t)b * PARTN + tid * NCH + j];
                v = (comp == 2) ? fmaxf(v, x) : (v + x);
            }
            svals[tid] = v;
        }
        __syncthreads();
        if (tid == 0) {
            float best = -1e30f; int bi = 0;
            for (int k = 0; k < Kk; ++k) {
                float coef = 1.f;
                for (int j = 0; j < t - 1; ++j)
                    if (clampK((int)idxf[j * Bb + b]) == k) coef = -1.f;
                float sc = coef * svals[3 * k + 2] * zeta[k * Bb + b] *
                           expf(-0.5f * INVVAR * svals[3 * k + 0] / (svals[3 * k + 1] + EPSf));
                if (sc > best) { best = sc; bi = k; }
            }
            s_sel = bi;
            if (ch == 0) idxf[(t - 1) * Bb + b] = (float)bi;
        }
        __syncthreads();
        sel = s_sel;
    }

    int pix = ch * 512 + tid * 2;
    float P0, P1;
    if (t == 0) {
        P0 = P1 = 1.f;
    } else {
        float pr0 = 1.f, pr1 = 1.f;
        if (t > 1) {
            float2 p2 = ld2(Pbuf + (size_t)b * HW + pix);
            pr0 = p2.x; pr1 = p2.y;
        }
        float2 sh = ld2(shp + (size_t)(sel * Bb + b) * HW + pix);
        P0 = pr0 * (1.f - sh.x * pr0); P1 = pr1 * (1.f - sh.y * pr1);
        st2(Pbuf + (size_t)b * HW + pix, make_float2(P0, P1));
    }

    float acc[24];
#pragma unroll
    for (int k = 0; k < Kk; ++k) {
        float2 s = ld2(shp + (size_t)(k * Bb + b) * HW + pix);
        float2 v = ld2(sd  + (size_t)(k * Bb + b) * HW + pix);
        float m0 = s.x * P0, m1 = s.y * P1;
        acc[3 * k + 0] = v.x * P0 + v.y * P1;
        acc[3 * k + 1] = m0 + m1;
        acc[3 * k + 2] = fmaxf(m0, m1);
    }

    __shared__ float ls[128][25];
    if (tid >= 128) {
#pragma unroll
        for (int q = 0; q < 24; ++q) ls[tid - 128][q] = acc[q];
    }
    __syncthreads();
    if (tid < 128) {
#pragma unroll
        for (int q = 0; q < 24; ++q) {
            float o = ls[tid][q];
            ls[tid][q] = (q % 3 == 2) ? fmaxf(acc[q], o) : (acc[q] + o);
        }
    }
    __syncthreads();
    for (int st = 64; st > 0; st >>= 1) {
        if (tid < st) {
#pragma unroll
            for (int q = 0; q < 24; ++q) {
                float o = ls[tid + st][q];
                ls[tid][q] = (q % 3 == 2) ? fmaxf(ls[tid][q], o) : (ls[tid][q] + o);
            }
        }
        __syncthreads();
    }
    if (tid < 24) partials_cur[(size_t)b * PARTN + tid * NCH + ch] = ls[0][tid];
}

// ---------------------------------------------------------------------------
// k_final: compute idx(7) from partials(7) + history, write idxf[7].
// grid: 32 x 64
// ---------------------------------------------------------------------------
__global__ __launch_bounds__(64) void k_final(
    const float* __restrict__ partials, const float* __restrict__ zeta,
    float* idxf)
{
    int b = blockIdx.x, tid = threadIdx.x;
    __shared__ float vals[24];
    if (tid < 24) {
        int comp = tid % 3;
        float v = (comp == 2) ? -1e30f : 0.f;
        for (int j = 0; j < NCH; ++j) {
            float x = partials[(size_t)b * PARTN + tid * NCH + j];
            v = (comp == 2) ? fmaxf(v, x) : (v + x);
        }
        vals[tid] = v;
    }
    __syncthreads();
    if (tid == 0) {
        float best = -1e30f; int bi = 0;
        for (int k = 0; k < Kk; ++k) {
            float coef = 1.f;
            for (int j = 0; j < 7; ++j)
                if (clampK((int)idxf[j * Bb + b]) == k) coef = -1.f;
            float sc = coef * vals[3 * k + 2] * zeta[k * Bb + b] *
                       expf(-0.5f * INVVAR * vals[3 * k + 0] / (vals[3 * k + 1] + EPSf));
            if (sc > best) { best = sc; bi = k; }
        }
        idxf[7 * Bb + b] = (float)bi;
    }
}

// ---------------------------------------------------------------------------
// Kernel 4: out[1+t] = apc[idx[t]]  (float4 copy). grid: 27648 x 256.
// ---------------------------------------------------------------------------
__global__ __launch_bounds__(256) void k_gather(
    const float* __restrict__ apc, const float* __restrict__ idxf,
    float* __restrict__ out)
{
    int g = blockIdx.x * 256 + threadIdx.x;   // float4 id over K*B*CHW4
    int tb = g / CHW4;
    int off = g - tb * CHW4;
    int t = tb >> 5, b = tb & 31;
    int s = clampK((int)idxf[t * Bb + b]);
    const float4* src = reinterpret_cast<const float4*>(apc) + (size_t)(s * Bb + b) * CHW4 + off;
    float4* dst = reinterpret_cast<float4*>(out) + (size_t)((1 + t) * Bb + b) * CHW4 + off;
    *dst = *src;
}

// ---------------------------------------------------------------------------
// Round 8: (1) float2 grids (2304 blocks) for k_pre/k_red -> 9 waves/SIMD
// supply (round 7 was grid-starved at 4.5); (2) k_score fused into k_red
// (+k_final) -> launches 18 -> 11; (3) partials ping-pong (A/B) to avoid
// same-kernel read/write overlap. No shuffles (condemned as the crasher).
// ---------------------------------------------------------------------------
extern "C" void kernel_launch(void* const* d_in, const int* in_sizes, int n_in,
                              void* d_out, int out_size, void* d_ws, size_t ws_size,
                              hipStream_t stream)
{
    const float *images = nullptr, *apc = nullptr, *shp = nullptr;
    const float *zeta = nullptr, *back = nullptr;
    for (int i = 0; i < n_in; ++i) {
        int s = in_sizes[i];
        if (s == 28311552)      apc  = (const float*)d_in[i];
        else if (s == 9437184)  shp  = (const float*)d_in[i];
        else if (s == 256)      zeta = (const float*)d_in[i];
        else if (s == 3538944) {
            if (!images) images = (const float*)d_in[i];
            else         back   = (const float*)d_in[i];
        }
    }
    if (!images || !apc || !shp || !zeta || !back) {   // fallback: dict order
        images = (const float*)d_in[0]; apc = (const float*)d_in[1];
        shp = (const float*)d_in[2]; zeta = (const float*)d_in[3];
        back = (const float*)d_in[4];
    }
    float* out = (float*)d_out;
    float* idxf = out + OUTMAIN;                       // 256-element tail

    // Scratch: sd(9437184) + Pbuf(1179648) + pA(55296) + pB(55296) = 42.9MB
    float* sd = (d_ws != nullptr && ws_size >= (size_t)48 * 1024 * 1024)
                  ? (float*)d_ws
                  : (out + BCHW);    // alias into out[1..8], dead before gather
    float* Pbuf = sd + 9437184;
    float* pA   = Pbuf + 1179648;
    float* pB   = pA + 55296;

    k_pre_fused<<<2304, 256, 0, stream>>>(images, apc, shp, zeta, back, out, sd);
    for (int t = 0; t < Kk; ++t) {
        float* prev = (t & 1) ? pA : pB;   // red(t) reads bufs[(t-1)&1]
        float* cur  = (t & 1) ? pB : pA;   // red(t) writes bufs[t&1]
        k_red_fast<<<2304, 256, 0, stream>>>(shp, sd, Pbuf, idxf, zeta, prev, cur, t);
    }
    k_final<<<32, 64, 0, stream>>>(pB, zeta, idxf);    // partials(7) = bufs[1] = pB
    k_gather<<<27648, 256, 0, stream>>>(apc, idxf, out);
}

// Round 9
// 239.454 us; speedup vs baseline: 1.0970x; 1.0970x over previous
//
#include <hip/hip_runtime.h>
#include <math.h>

#define Kk 8
#define Bb 32
#define Cc 3
#define HW 36864          // 192*192
#define HW4 9216          // float4s per plane
#define CHW 110592        // 3*HW
#define CHW4 27648        // float4s per (k,b) image
#define BCHW 3538944      // B*C*HW
#define OUTMAIN 31850496  // 9*BCHW : index tail start in d_out (elements)
#define NCH 36            // chunks per batch in k_red (1024 px each)
#define PARTN 864         // 24*NCH per batch
#define INVVAR 11.11111111111111f
#define EPSf 1e-5f

__device__ __forceinline__ int clampK(int v) { return v < 0 ? 0 : (v > Kk - 1 ? Kk - 1 : v); }
__device__ __forceinline__ float4 ld4(const float* p) { return *reinterpret_cast<const float4*>(p); }
__device__ __forceinline__ void st4(float* p, float4 v) { *reinterpret_cast<float4*>(p) = v; }

// ---------------------------------------------------------------------------
// Kernel 1: recon -> out[0] AND sd = shp*sum_c(apc-img)^2.
// float4/thread; loads hoisted in 2 batches of 16 (k=0..3, k=4..7) so ~16
// loads are in flight before any waitcnt. 1152 blocks x 256.
// ---------------------------------------------------------------------------
__global__ __launch_bounds__(256, 3) void k_pre_fused(
    const float* __restrict__ images, const float* __restrict__ apc,
    const float* __restrict__ shp, const float* __restrict__ zeta,
    const float* __restrict__ back, float* __restrict__ out,
    float* __restrict__ sd)
{
    int gid = blockIdx.x * 256 + threadIdx.x;     // float4 id over B*HW4
    int b = gid / HW4;
    int pix = (gid - b * HW4) * 4;

    float4 img[Cc], bk[Cc], rec[Cc];
#pragma unroll
    for (int c = 0; c < Cc; ++c) {
        img[c] = ld4(images + (size_t)(b * Cc + c) * HW + pix);
        bk[c]  = ld4(back   + (size_t)(b * Cc + c) * HW + pix);
        rec[c] = make_float4(0.f, 0.f, 0.f, 0.f);
    }
    float cum0 = 1.f, cum1 = 1.f, cum2 = 1.f, cum3 = 1.f;

#pragma unroll
    for (int half = 0; half < 2; ++half) {
        int k0 = half * 4;
        // ---- hoisted load batch: 4 shp + 12 apc float4s, no uses between ----
        float4 s[4], a[4][Cc];
#pragma unroll
        for (int kk = 0; kk < 4; ++kk)
            s[kk] = ld4(shp + (size_t)((k0 + kk) * Bb + b) * HW + pix);
#pragma unroll
        for (int kk = 0; kk < 4; ++kk)
#pragma unroll
            for (int c = 0; c < Cc; ++c)
                a[kk][c] = ld4(apc + ((size_t)((k0 + kk) * Bb + b) * Cc + c) * HW + pix);
        // ---- compute ----
#pragma unroll
        for (int kk = 0; kk < 4; ++kk) {
            int k = k0 + kk;
            float z = zeta[k * Bb + b];
            float x0 = s[kk].x * z, x1 = s[kk].y * z, x2 = s[kk].z * z, x3 = s[kk].w * z;
            float g0 = x0 * cum0, g1 = x1 * cum1, g2 = x2 * cum2, g3 = x3 * cum3;
            float df0 = 0.f, df1 = 0.f, df2 = 0.f, df3 = 0.f;
#pragma unroll
            for (int c = 0; c < Cc; ++c) {
                float4 av = a[kk][c];
                float d0 = av.x - img[c].x, d1 = av.y - img[c].y;
                float d2 = av.z - img[c].z, d3 = av.w - img[c].w;
                df0 += d0 * d0; df1 += d1 * d1; df2 += d2 * d2; df3 += d3 * d3;
                rec[c].x += g0 * av.x; rec[c].y += g1 * av.y;
                rec[c].z += g2 * av.z; rec[c].w += g3 * av.w;
            }
            st4(sd + (size_t)(k * Bb + b) * HW + pix,
                make_float4(s[kk].x * df0, s[kk].y * df1, s[kk].z * df2, s[kk].w * df3));
            cum0 *= (1.f - x0); cum1 *= (1.f - x1); cum2 *= (1.f - x2); cum3 *= (1.f - x3);
        }
    }
#pragma unroll
    for (int c = 0; c < Cc; ++c) {
        st4(out + (size_t)(b * Cc + c) * HW + pix,
            make_float4(rec[c].x + cum0 * bk[c].x, rec[c].y + cum1 * bk[c].y,
                        rec[c].z + cum2 * bk[c].z, rec[c].w + cum3 * bk[c].w));
    }
}

// ---------------------------------------------------------------------------
// Kernel 2 (step t): [t>0: inline score of step t-1 -> sel, ch==0 block
// writes idxf[t-1]], update persistent P, reduce {sum sd*P, sum shp*P,
// max shp*P}. ALL global loads hoisted (8 shp + 8 sd + sel-plane + Pbuf).
// float4/thread, 1152 blocks x 256, LDS tree (no shuffles).
// partials: [b][24][NCH].
// ---------------------------------------------------------------------------
__global__ __launch_bounds__(256, 4) void k_red_fast(
    const float* __restrict__ shp, const float* __restrict__ sd,
    float* __restrict__ Pbuf, float* idxf, const float* __restrict__ zeta,
    const float* __restrict__ partials_prev, float* __restrict__ partials_cur,
    int t)
{
    int b = blockIdx.x / NCH, ch = blockIdx.x % NCH;
    int tid = threadIdx.x;

    __shared__ float svals[24];
    __shared__ int s_sel;
    int sel = 0;
    if (t > 0) {
        if (tid < 24) {
            int comp = tid % 3;
            float v = (comp == 2) ? -1e30f : 0.f;
            for (int j = 0; j < NCH; ++j) {
                float x = partials_prev[(size_t)b * PARTN + tid * NCH + j];
                v = (comp == 2) ? fmaxf(v, x) : (v + x);
            }
            svals[tid] = v;
        }
        __syncthreads();
        if (tid == 0) {
            float best = -1e30f; int bi = 0;
            for (int k = 0; k < Kk; ++k) {
                float coef = 1.f;
                for (int j = 0; j < t - 1; ++j)
                    if (clampK((int)idxf[j * Bb + b]) == k) coef = -1.f;
                float sc = coef * svals[3 * k + 2] * zeta[k * Bb + b] *
                           expf(-0.5f * INVVAR * svals[3 * k + 0] / (svals[3 * k + 1] + EPSf));
                if (sc > best) { best = sc; bi = k; }
            }
            s_sel = bi;
            if (ch == 0) idxf[(t - 1) * Bb + b] = (float)bi;
        }
        __syncthreads();
        sel = s_sel;
    }

    int pix = ch * 1024 + tid * 4;

    // ---- hoisted load batch: 8 shp + 8 sd + sel-plane + Pbuf ----
    float4 s[Kk], v[Kk];
#pragma unroll
    for (int k = 0; k < Kk; ++k) s[k] = ld4(shp + (size_t)(k * Bb + b) * HW + pix);
#pragma unroll
    for (int k = 0; k < Kk; ++k) v[k] = ld4(sd + (size_t)(k * Bb + b) * HW + pix);
    float4 sh = make_float4(0.f, 0.f, 0.f, 0.f);
    float4 pold = make_float4(1.f, 1.f, 1.f, 1.f);
    if (t > 0) sh = ld4(shp + (size_t)(sel * Bb + b) * HW + pix);   // static idx (rule #20)
    if (t > 1) pold = ld4(Pbuf + (size_t)b * HW + pix);

    // ---- P update ----
    float P0, P1, P2, P3;
    if (t == 0) {
        P0 = P1 = P2 = P3 = 1.f;
    } else {
        P0 = pold.x * (1.f - sh.x * pold.x); P1 = pold.y * (1.f - sh.y * pold.y);
        P2 = pold.z * (1.f - sh.z * pold.z); P3 = pold.w * (1.f - sh.w * pold.w);
        st4(Pbuf + (size_t)b * HW + pix, make_float4(P0, P1, P2, P3));
    }

    float acc[24];
#pragma unroll
    for (int k = 0; k < Kk; ++k) {
        float m0 = s[k].x * P0, m1 = s[k].y * P1, m2 = s[k].z * P2, m3 = s[k].w * P3;
        acc[3 * k + 0] = (v[k].x * P0 + v[k].y * P1) + (v[k].z * P2 + v[k].w * P3);
        acc[3 * k + 1] = (m0 + m1) + (m2 + m3);
        acc[3 * k + 2] = fmaxf(fmaxf(m0, m1), fmaxf(m2, m3));
    }

    __shared__ float ls[128][25];
    if (tid >= 128) {
#pragma unroll
        for (int q = 0; q < 24; ++q) ls[tid - 128][q] = acc[q];
    }
    __syncthreads();
    if (tid < 128) {
#pragma unroll
        for (int q = 0; q < 24; ++q) {
            float o = ls[tid][q];
            ls[tid][q] = (q % 3 == 2) ? fmaxf(acc[q], o) : (acc[q] + o);
        }
    }
    __syncthreads();
    for (int st = 64; st > 0; st >>= 1) {
        if (tid < st) {
#pragma unroll
            for (int q = 0; q < 24; ++q) {
                float o = ls[tid + st][q];
                ls[tid][q] = (q % 3 == 2) ? fmaxf(ls[tid][q], o) : (ls[tid][q] + o);
            }
        }
        __syncthreads();
    }
    if (tid < 24) partials_cur[(size_t)b * PARTN + tid * NCH + ch] = ls[0][tid];
}

// ---------------------------------------------------------------------------
// k_final: idx(7) from partials(7) + history. grid: 32 x 64.
// ---------------------------------------------------------------------------
__global__ __launch_bounds__(64) void k_final(
    const float* __restrict__ partials, const float* __restrict__ zeta,
    float* idxf)
{
    int b = blockIdx.x, tid = threadIdx.x;
    __shared__ float vals[24];
    if (tid < 24) {
        int comp = tid % 3;
        float v = (comp == 2) ? -1e30f : 0.f;
        for (int j = 0; j < NCH; ++j) {
            float x = partials[(size_t)b * PARTN + tid * NCH + j];
            v = (comp == 2) ? fmaxf(v, x) : (v + x);
        }
        vals[tid] = v;
    }
    __syncthreads();
    if (tid == 0) {
        float best = -1e30f; int bi = 0;
        for (int k = 0; k < Kk; ++k) {
            float coef = 1.f;
            for (int j = 0; j < 7; ++j)
                if (clampK((int)idxf[j * Bb + b]) == k) coef = -1.f;
            float sc = coef * vals[3 * k + 2] * zeta[k * Bb + b] *
                       expf(-0.5f * INVVAR * vals[3 * k + 0] / (vals[3 * k + 1] + EPSf));
            if (sc > best) { best = sc; bi = k; }
        }
        idxf[7 * Bb + b] = (float)bi;
    }
}

// ---------------------------------------------------------------------------
// Kernel 4: out[1+t] = apc[idx[t]]. 4 float4/thread, loads hoisted.
// grid: 6912 blocks x 256 (27 chunks of 1024 float4 per image).
// ---------------------------------------------------------------------------
__global__ __launch_bounds__(256) void k_gather(
    const float* __restrict__ apc, const float* __restrict__ idxf,
    float* __restrict__ out)
{
    int image = blockIdx.x / 27;           // 0..255 == t*32+b
    int chunk = blockIdx.x % 27;
    int t = image >> 5, b = image & 31;
    int s = clampK((int)idxf[t * Bb + b]);
    const float4* src = reinterpret_cast<const float4*>(apc) + (size_t)(s * Bb + b) * CHW4;
    float4* dst = reinterpret_cast<float4*>(out) + (size_t)(image + Bb) * CHW4;
    int base = chunk * 1024 + threadIdx.x;
    float4 r0 = src[base];
    float4 r1 = src[base + 256];
    float4 r2 = src[base + 512];
    float4 r3 = src[base + 768];
    dst[base]       = r0;
    dst[base + 256] = r1;
    dst[base + 512] = r2;
    dst[base + 768] = r3;
}

// ---------------------------------------------------------------------------
// Round 9: explicit load-hoisting (MLP) experiment. Rounds 6/7/8 were flat
// (~75us k_pre) across scalar/float2/float4 and 25-47% occupancy; VGPR 44-84
// says the compiler never kept >8 loads in flight. This round forces 16-18
// hoisted loads/thread via batched loads + launch_bounds VGPR headroom.
// Logic identical to round 8 (passed). No shuffles.
// ---------------------------------------------------------------------------
extern "C" void kernel_launch(void* const* d_in, const int* in_sizes, int n_in,
                              void* d_out, int out_size, void* d_ws, size_t ws_size,
                              hipStream_t stream)
{
    const float *images = nullptr, *apc = nullptr, *shp = nullptr;
    const float *zeta = nullptr, *back = nullptr;
    for (int i = 0; i < n_in; ++i) {
        int s = in_sizes[i];
        if (s == 28311552)      apc  = (const float*)d_in[i];
        else if (s == 9437184)  shp  = (const float*)d_in[i];
        else if (s == 256)      zeta = (const float*)d_in[i];
        else if (s == 3538944) {
            if (!images) images = (const float*)d_in[i];
            else         back   = (const float*)d_in[i];
        }
    }
    if (!images || !apc || !shp || !zeta || !back) {   // fallback: dict order
        images = (const float*)d_in[0]; apc = (const float*)d_in[1];
        shp = (const float*)d_in[2]; zeta = (const float*)d_in[3];
        back = (const float*)d_in[4];
    }
    float* out = (float*)d_out;
    float* idxf = out + OUTMAIN;                       // 256-element tail

    // Scratch: sd(9437184) + Pbuf(1179648) + pA(27648) + pB(27648) = 42.7MB
    float* sd = (d_ws != nullptr && ws_size >= (size_t)48 * 1024 * 1024)
                  ? (float*)d_ws
                  : (out + BCHW);    // alias into out[1..8], dead before gather
    float* Pbuf = sd + 9437184;
    float* pA   = Pbuf + 1179648;
    float* pB   = pA + 27648;

    k_pre_fused<<<1152, 256, 0, stream>>>(images, apc, shp, zeta, back, out, sd);
    for (int t = 0; t < Kk; ++t) {
        float* prev = (t & 1) ? pA : pB;   // red(t) reads bufs[(t-1)&1]
        float* cur  = (t & 1) ? pB : pA;   // red(t) writes bufs[t&1]
        k_red_fast<<<1152, 256, 0, stream>>>(shp, sd, Pbuf, idxf, zeta, prev, cur, t);
    }
    k_final<<<32, 64, 0, stream>>>(pB, zeta, idxf);    // partials(7) in pB
    k_gather<<<6912, 256, 0, stream>>>(apc, idxf, out);
}

// Round 10
// 235.505 us; speedup vs baseline: 1.1154x; 1.0168x over previous
//
#include <hip/hip_runtime.h>
#include <math.h>

#define Kk 8
#define Bb 32
#define Cc 3
#define HW 36864          // 192*192
#define HW4 9216          // float4s per plane
#define CHW 110592        // 3*HW
#define CHW4 27648        // float4s per (k,b) image
#define BCHW 3538944      // B*C*HW
#define OUTMAIN 31850496  // 9*BCHW : index tail start in d_out (elements)
#define NCH 36            // chunks per batch (1024 px each)
#define PARTN 864         // 24*NCH per batch
#define INVVAR 11.11111111111111f
#define EPSf 1e-5f

__device__ __forceinline__ int clampK(int v) { return v < 0 ? 0 : (v > Kk - 1 ? Kk - 1 : v); }
__device__ __forceinline__ float4 ld4(const float* p) { return *reinterpret_cast<const float4*>(p); }
__device__ __forceinline__ void st4(float* p, float4 v) { *reinterpret_cast<float4*>(p) = v; }

// ---------------------------------------------------------------------------
// Kernel 1: recon -> out[0], sd = shp*sum_c(apc-img)^2, AND the t=0 step
// reduction (P==1: acc = plane sums of sd / shp / max shp) -> partials0.
// Replaces round-9's k_pre + k_red(0): saves red0's 85MB cache re-read.
// grid: 1152 x 256, 1 float4/thread. LDS tree identical pairing to k_red.
// ---------------------------------------------------------------------------
__global__ __launch_bounds__(256, 3) void k_pre_red0(
    const float* __restrict__ images, const float* __restrict__ apc,
    const float* __restrict__ shp, const float* __restrict__ zeta,
    const float* __restrict__ back, float* __restrict__ out,
    float* __restrict__ sd, float* __restrict__ partials0)
{
    int tid = threadIdx.x;
    int b = blockIdx.x / NCH, ch = blockIdx.x % NCH;   // HW4 = NCH*256 exactly
    int pix = ch * 1024 + tid * 4;

    float4 img[Cc], bk[Cc], rec[Cc];
#pragma unroll
    for (int c = 0; c < Cc; ++c) {
        img[c] = ld4(images + (size_t)(b * Cc + c) * HW + pix);
        bk[c]  = ld4(back   + (size_t)(b * Cc + c) * HW + pix);
        rec[c] = make_float4(0.f, 0.f, 0.f, 0.f);
    }
    float cum0 = 1.f, cum1 = 1.f, cum2 = 1.f, cum3 = 1.f;
    float acc[24];

#pragma unroll
    for (int k = 0; k < Kk; ++k) {
        float4 s = ld4(shp + (size_t)(k * Bb + b) * HW + pix);
        float z = zeta[k * Bb + b];
        float x0 = s.x * z, x1 = s.y * z, x2 = s.z * z, x3 = s.w * z;
        float g0 = x0 * cum0, g1 = x1 * cum1, g2 = x2 * cum2, g3 = x3 * cum3;
        float df0 = 0.f, df1 = 0.f, df2 = 0.f, df3 = 0.f;
#pragma unroll
        for (int c = 0; c < Cc; ++c) {
            float4 av = ld4(apc + ((size_t)(k * Bb + b) * Cc + c) * HW + pix);
            float d0 = av.x - img[c].x, d1 = av.y - img[c].y;
            float d2 = av.z - img[c].z, d3 = av.w - img[c].w;
            df0 += d0 * d0; df1 += d1 * d1; df2 += d2 * d2; df3 += d3 * d3;
            rec[c].x += g0 * av.x; rec[c].y += g1 * av.y;
            rec[c].z += g2 * av.z; rec[c].w += g3 * av.w;
        }
        float4 sdv = make_float4(s.x * df0, s.y * df1, s.z * df2, s.w * df3);
        st4(sd + (size_t)(k * Bb + b) * HW + pix, sdv);
        // t=0 reduction terms (P==1), same pairing as k_red_fast:
        acc[3 * k + 0] = (sdv.x + sdv.y) + (sdv.z + sdv.w);
        acc[3 * k + 1] = (s.x + s.y) + (s.z + s.w);
        acc[3 * k + 2] = fmaxf(fmaxf(s.x, s.y), fmaxf(s.z, s.w));
        cum0 *= (1.f - x0); cum1 *= (1.f - x1); cum2 *= (1.f - x2); cum3 *= (1.f - x3);
    }
#pragma unroll
    for (int c = 0; c < Cc; ++c) {
        st4(out + (size_t)(b * Cc + c) * HW + pix,
            make_float4(rec[c].x + cum0 * bk[c].x, rec[c].y + cum1 * bk[c].y,
                        rec[c].z + cum2 * bk[c].z, rec[c].w + cum3 * bk[c].w));
    }

    __shared__ float ls[128][25];
    if (tid >= 128) {
#pragma unroll
        for (int q = 0; q < 24; ++q) ls[tid - 128][q] = acc[q];
    }
    __syncthreads();
    if (tid < 128) {
#pragma unroll
        for (int q = 0; q < 24; ++q) {
            float o = ls[tid][q];
            ls[tid][q] = (q % 3 == 2) ? fmaxf(acc[q], o) : (acc[q] + o);
        }
    }
    __syncthreads();
    for (int st = 64; st > 0; st >>= 1) {
        if (tid < st) {
#pragma unroll
            for (int q = 0; q < 24; ++q) {
                float o = ls[tid + st][q];
                ls[tid][q] = (q % 3 == 2) ? fmaxf(ls[tid][q], o) : (ls[tid][q] + o);
            }
        }
        __syncthreads();
    }
    if (tid < 24) partials0[(size_t)b * PARTN + tid * NCH + ch] = ls[0][tid];
}

// ---------------------------------------------------------------------------
// Kernel 2 (step t = 1..7): inline score of step t-1 -> sel (ch==0 writes
// idxf[t-1]), update persistent P, reduce {sum sd*P, sum shp*P, max shp*P}.
// Unchanged from round 9 (proven). grid: 1152 x 256.
// ---------------------------------------------------------------------------
__global__ __launch_bounds__(256, 4) void k_red_fast(
    const float* __restrict__ shp, const float* __restrict__ sd,
    float* __restrict__ Pbuf, float* idxf, const float* __restrict__ zeta,
    const float* __restrict__ partials_prev, float* __restrict__ partials_cur,
    int t)
{
    int b = blockIdx.x / NCH, ch = blockIdx.x % NCH;
    int tid = threadIdx.x;

    __shared__ float svals[24];
    __shared__ int s_sel;
    if (tid < 24) {
        int comp = tid % 3;
        float v = (comp == 2) ? -1e30f : 0.f;
        for (int j = 0; j < NCH; ++j) {
            float x = partials_prev[(size_t)b * PARTN + tid * NCH + j];
            v = (comp == 2) ? fmaxf(v, x) : (v + x);
        }
        svals[tid] = v;
    }
    __syncthreads();
    if (tid == 0) {
        float best = -1e30f; int bi = 0;
        for (int k = 0; k < Kk; ++k) {
            float coef = 1.f;
            for (int j = 0; j < t - 1; ++j)
                if (clampK((int)idxf[j * Bb + b]) == k) coef = -1.f;
            float sc = coef * svals[3 * k + 2] * zeta[k * Bb + b] *
                       expf(-0.5f * INVVAR * svals[3 * k + 0] / (svals[3 * k + 1] + EPSf));
            if (sc > best) { best = sc; bi = k; }
        }
        s_sel = bi;
        if (ch == 0) idxf[(t - 1) * Bb + b] = (float)bi;
    }
    __syncthreads();
    int sel = s_sel;

    int pix = ch * 1024 + tid * 4;

    float4 s[Kk], v[Kk];
#pragma unroll
    for (int k = 0; k < Kk; ++k) s[k] = ld4(shp + (size_t)(k * Bb + b) * HW + pix);
#pragma unroll
    for (int k = 0; k < Kk; ++k) v[k] = ld4(sd + (size_t)(k * Bb + b) * HW + pix);
    float4 sh = ld4(shp + (size_t)(sel * Bb + b) * HW + pix);
    float4 pold = make_float4(1.f, 1.f, 1.f, 1.f);
    if (t > 1) pold = ld4(Pbuf + (size_t)b * HW + pix);

    float P0 = pold.x * (1.f - sh.x * pold.x), P1 = pold.y * (1.f - sh.y * pold.y);
    float P2 = pold.z * (1.f - sh.z * pold.z), P3 = pold.w * (1.f - sh.w * pold.w);
    st4(Pbuf + (size_t)b * HW + pix, make_float4(P0, P1, P2, P3));

    float acc[24];
#pragma unroll
    for (int k = 0; k < Kk; ++k) {
        float m0 = s[k].x * P0, m1 = s[k].y * P1, m2 = s[k].z * P2, m3 = s[k].w * P3;
        acc[3 * k + 0] = (v[k].x * P0 + v[k].y * P1) + (v[k].z * P2 + v[k].w * P3);
        acc[3 * k + 1] = (m0 + m1) + (m2 + m3);
        acc[3 * k + 2] = fmaxf(fmaxf(m0, m1), fmaxf(m2, m3));
    }

    __shared__ float ls[128][25];
    if (tid >= 128) {
#pragma unroll
        for (int q = 0; q < 24; ++q) ls[tid - 128][q] = acc[q];
    }
    __syncthreads();
    if (tid < 128) {
#pragma unroll
        for (int q = 0; q < 24; ++q) {
            float o = ls[tid][q];
            ls[tid][q] = (q % 3 == 2) ? fmaxf(acc[q], o) : (acc[q] + o);
        }
    }
    __syncthreads();
    for (int st = 64; st > 0; st >>= 1) {
        if (tid < st) {
#pragma unroll
            for (int q = 0; q < 24; ++q) {
                float o = ls[tid + st][q];
                ls[tid][q] = (q % 3 == 2) ? fmaxf(ls[tid][q], o) : (ls[tid][q] + o);
            }
        }
        __syncthreads();
    }
    if (tid < 24) partials_cur[(size_t)b * PARTN + tid * NCH + ch] = ls[0][tid];
}

// ---------------------------------------------------------------------------
// Kernel 3: out[1+t] = apc[idx[t]] (4 float4/thread) WITH the final (t=7)
// argmax fused: t==7 blocks self-compute idx7 from partials(7) (block-uniform
// branch); (t==7, chunk==0) also writes idxf[7]. grid: 6912 x 256.
// ---------------------------------------------------------------------------
__global__ __launch_bounds__(256) void k_gather(
    const float* __restrict__ apc, const float* __restrict__ partials7,
    const float* __restrict__ zeta, float* idxf, float* __restrict__ out)
{
    int image = blockIdx.x / 27;           // 0..255 == t*32+b
    int chunk = blockIdx.x % 27;
    int t = image >> 5, b = image & 31;
    int tid = threadIdx.x;

    int s;
    if (t == 7) {
        __shared__ float vals[24];
        __shared__ int s_sel;
        if (tid < 24) {
            int comp = tid % 3;
            float v = (comp == 2) ? -1e30f : 0.f;
            for (int j = 0; j < NCH; ++j) {
                float x = partials7[(size_t)b * PARTN + tid * NCH + j];
                v = (comp == 2) ? fmaxf(v, x) : (v + x);
            }
            vals[tid] = v;
        }
        __syncthreads();
        if (tid == 0) {
            float best = -1e30f; int bi = 0;
            for (int k = 0; k < Kk; ++k) {
                float coef = 1.f;
                for (int j = 0; j < 7; ++j)
                    if (clampK((int)idxf[j * Bb + b]) == k) coef = -1.f;
                float sc = coef * vals[3 * k + 2] * zeta[k * Bb + b] *
                           expf(-0.5f * INVVAR * vals[3 * k + 0] / (vals[3 * k + 1] + EPSf));
                if (sc > best) { best = sc; bi = k; }
            }
            s_sel = bi;
            if (chunk == 0) idxf[7 * Bb + b] = (float)bi;
        }
        __syncthreads();
        s = s_sel;
    } else {
        s = clampK((int)idxf[t * Bb + b]);
    }

    const float4* src = reinterpret_cast<const float4*>(apc) + (size_t)(s * Bb + b) * CHW4;
    float4* dst = reinterpret_cast<float4*>(out) + (size_t)(image + Bb) * CHW4;
    int base = chunk * 1024 + tid;
    float4 r0 = src[base];
    float4 r1 = src[base + 256];
    float4 r2 = src[base + 512];
    float4 r3 = src[base + 768];
    dst[base]       = r0;
    dst[base + 256] = r1;
    dst[base + 512] = r2;
    dst[base + 768] = r3;
}

// ---------------------------------------------------------------------------
// Round 10: t=0 reduction fused into k_pre (red0's 85MB cache re-read + one
// launch eliminated); k_final fused into k_gather (one more launch). Steps
// 1..7 and gather bodies byte-identical to round 9 (proven). 9 launches.
// No shuffles (condemned). Bit-exact partials/index chain vs round 9.
// ---------------------------------------------------------------------------
extern "C" void kernel_launch(void* const* d_in, const int* in_sizes, int n_in,
                              void* d_out, int out_size, void* d_ws, size_t ws_size,
                              hipStream_t stream)
{
    const float *images = nullptr, *apc = nullptr, *shp = nullptr;
    const float *zeta = nullptr, *back = nullptr;
    for (int i = 0; i < n_in; ++i) {
        int s = in_sizes[i];
        if (s == 28311552)      apc  = (const float*)d_in[i];
        else if (s == 9437184)  shp  = (const float*)d_in[i];
        else if (s == 256)      zeta = (const float*)d_in[i];
        else if (s == 3538944) {
            if (!images) images = (const float*)d_in[i];
            else         back   = (const float*)d_in[i];
        }
    }
    if (!images || !apc || !shp || !zeta || !back) {   // fallback: dict order
        images = (const float*)d_in[0]; apc = (const float*)d_in[1];
        shp = (const float*)d_in[2]; zeta = (const float*)d_in[3];
        back = (const float*)d_in[4];
    }
    float* out = (float*)d_out;
    float* idxf = out + OUTMAIN;                       // 256-element tail

    // Scratch: sd(9437184) + Pbuf(1179648) + pA(27648) + pB(27648) = 42.7MB
    float* sd = (d_ws != nullptr && ws_size >= (size_t)48 * 1024 * 1024)
                  ? (float*)d_ws
                  : (out + BCHW);    // alias into out[1..8], dead before gather
    float* Pbuf = sd + 9437184;
    float* pA   = Pbuf + 1179648;
    float* pB   = pA + 27648;

    // partials(0) -> pA (matches round-9 ping-pong: red(t) reads (t&1)?pA:pB)
    k_pre_red0<<<1152, 256, 0, stream>>>(images, apc, shp, zeta, back, out, sd, pA);
    for (int t = 1; t < Kk; ++t) {
        float* prev = (t & 1) ? pA : pB;
        float* cur  = (t & 1) ? pB : pA;
        k_red_fast<<<1152, 256, 0, stream>>>(shp, sd, Pbuf, idxf, zeta, prev, cur, t);
    }
    // partials(7): t=7 -> cur = pB
    k_gather<<<6912, 256, 0, stream>>>(apc, pB, zeta, idxf, out);
}